// Round 3
// baseline (3906.616 us; speedup 1.0000x reference)
//
#include <hip/hip_runtime.h>

// ---------------------------------------------------------------------------
// arGDPmax_net: 80-step coupled GRU (SDC 128 / world 3968 rows, H=512)
// + segment-max coupling + per-step MLP head.
//
// Round-3 changes vs round-2 (3128us, absmax 0.0195):
//  - ONE kernel per step (k_step). The 64 sdc blocks, after finishing sh(t),
//    pass an intra-kernel agent-scope barrier (spin counter), clear the stale
//    segmax buffer and compute G(t+1)=sh(t)@wld_WiT+bi into double-buffered G
//    -- all hidden under the 496 world blocks' GEMM. k_small is gone.
//  - k_big0 converted to gload16 staging (was reg-staged, 77us).
//  - k_g1 (one launch) seeds G(1) from sh(0).
// ---------------------------------------------------------------------------

typedef __attribute__((ext_vector_type(8))) short short8;
typedef __attribute__((ext_vector_type(4))) float f32x4;
typedef unsigned short u16;
typedef unsigned int u32;

#define DEV __device__ __forceinline__

constexpr int S  = 128;
constexpr int NR = 4096;
constexpr int H  = 512;
constexpr int TH = 1536;
constexpr int SLOT = NR * H;
constexpr int SEGSZ = S * H;       // u32 elems per segmax buffer
constexpr int GSZ = S * TH;        // f32 elems per G buffer

struct P {
  const float *goals, *dyn, *ccls, *inte;
  const int *seg;
  const float *sdc_h0, *wld_h0;
  const float *golW, *golb;
  const float *sdcbi, *sdcbh, *wldbi, *wldbh;
  const float *sdco1b, *sdco2W, *sdco2b;
  const float *wldo1b, *wldo2W, *wldo2b;
  const float *sdcWi, *sdcWh, *wldWi, *wldWh, *sdco1W, *wldo1W;
  float *out;
  float *whf;      // [2][4096][512] f32 carried state
  u16   *ring;     // [8][4096][512] bf16 state history
  u16   *enc;      // [4096][512] bf16 encoder output (dead after t=0)
  u16   *WT;       // 4 x [1536][512] bf16: sdcWiT, sdcWhT, wldWiT, wldWhT
  u16   *o1T;      // 2 x [512][512] bf16
  float *G;        // [2][128][1536] f32 (double-buffered)
  u32   *segb;     // [2][128][512] flipped-uint segmax buffers
  u32   *spinc;    // [80] per-step arrival counters
  float *part;     // [4][32768][2] f32 MLP partials (aliases enc)
  int t;
};

DEV u16 f2bf(float f) {
  u32 u = __float_as_uint(f);
  u32 r = u + 0x7FFFu + ((u >> 16) & 1u);
  return (u16)(r >> 16);
}
DEV u32 flipf(float f) {
  u32 u = __float_as_uint(f);
  return (u & 0x80000000u) ? ~u : (u | 0x80000000u);
}
DEV float unflip(u32 s) {
  u32 u = (s & 0x80000000u) ? (s & 0x7FFFFFFFu) : ~s;
  return __uint_as_float(u);
}
DEV float sigm(float x)  { return 1.0f / (1.0f + __expf(-x)); }
DEV float tanh_(float x) { return 2.0f / (1.0f + __expf(-2.0f * x)) - 1.0f; }

DEV f32x4 mfma16(short8 a, short8 b, f32x4 c) {
  return __builtin_amdgcn_mfma_f32_16x16x32_bf16(a, b, c, 0, 0, 0);
}

// async global->LDS, 16B per lane. LDS dest = wave-uniform base + lane*16.
DEV void gload16(const void* g, void* l) {
  __builtin_amdgcn_global_load_lds(
      (const __attribute__((address_space(1))) void*)g,
      (__attribute__((address_space(3))) void*)l, 16, 0, 0);
}

// reg-staged tile: LDS unit (m,g) <- src unit (m, g^(m&7)).
DEV void stage_bf(u16* lds, const u16* src, int stride, int rows, int tid) {
  for (int u = tid; u < rows * 8; u += 256) {
    int m = u >> 3, g = u & 7, gs = g ^ (m & 7);
    *(short8*)(lds + (u << 3)) = *(const short8*)(src + m * stride + (gs << 3));
  }
}
// reg-staged from flipped-uint segmax buffer (unflip + cvt). 64 rows.
DEV void stage_seg(u16* lds, const u32* src, int stride, int tid) {
  for (int u = tid; u < 512; u += 256) {
    int m = u >> 3, g = u & 7, gs = g ^ (m & 7);
    const u32* pp = src + m * stride + (gs << 3);
    short8 v;
#pragma unroll
    for (int e = 0; e < 8; ++e) v[e] = (short)f2bf(unflip(pp[e]));
    *(short8*)(lds + (u << 3)) = v;
  }
}
// fragment read honoring the swizzle; row stride 64 elems (128B).
DEV short8 lds_frag(const u16* lds, int row, int g) {
  return *(const short8*)(lds + row * 64 + ((g ^ (row & 7)) << 3));
}

// intra-kernel device barrier over `target` arriving blocks.
DEV void arrive_wait(u32* cnt, int tid, u32 target) {
  __syncthreads();
  if (tid == 0) {
    __threadfence();
    __hip_atomic_fetch_add(cnt, 1u, __ATOMIC_ACQ_REL, __HIP_MEMORY_SCOPE_AGENT);
    while (__hip_atomic_load(cnt, __ATOMIC_ACQUIRE, __HIP_MEMORY_SCOPE_AGENT) < target)
      __builtin_amdgcn_s_sleep(8);
  }
  __syncthreads();
  __threadfence();
}

// ---------------------------------------------------------------------------
// k_prep: weight transposes, encoder, h0 copy, segb[0..1] clear, spinc clear.
// Grid 1032.
// ---------------------------------------------------------------------------
__global__ __launch_bounds__(256) void k_prep(P p) {
  const int b = blockIdx.x, tid = threadIdx.x;
  __shared__ u16 lt[64 * 72];
  if (b < 896) {
    int nt, kt, Nn; const float* src; u16* dst;
    if (b < 768) {
      int m = b / 192, t2 = b % 192;
      nt = t2 % 24; kt = t2 / 24; Nn = TH;
      src = (m == 0) ? p.sdcWi : (m == 1) ? p.sdcWh : (m == 2) ? p.wldWi : p.wldWh;
      dst = p.WT + m * TH * H;
    } else {
      int bb = b - 768, m = bb / 64, t2 = bb % 64;
      nt = t2 % 8; kt = t2 / 8; Nn = H;
      src = m ? p.wldo1W : p.sdco1W;
      dst = p.o1T + m * H * H;
    }
    for (int it = 0; it < 16; ++it) {
      int kl = it * 4 + (tid >> 6), nl = tid & 63;
      lt[nl * 72 + kl] = f2bf(src[(kt * 64 + kl) * Nn + nt * 64 + nl]);
    }
    __syncthreads();
    for (int it = 0; it < 2; ++it) {
      int nl = it * 32 + (tid >> 3), k8 = (tid & 7) * 8;
      *(short8*)(dst + (nt * 64 + nl) * H + kt * 64 + k8) =
          *(const short8*)(lt + nl * 72 + k8);
    }
  } else if (b < 960) {
    int r0 = (b - 896) * 64;
    for (int i = 0; i < 128; ++i) {
      int idx = i * 256 + tid, row = r0 + (idx >> 9), c = idx & 511;
      float v;
      if (c < 128)      v = p.goals[row*2]*p.golW[c] + p.goals[row*2+1]*p.golW[128+c] + p.golb[c];
      else if (c < 256) v = p.dyn [row*128 + c - 128];
      else if (c < 384) v = p.ccls[row*128 + c - 256];
      else              v = p.inte[row*128 + c - 384];
      p.enc[row * H + c] = f2bf(v);
    }
  } else if (b < 1024) {
    int r0 = (b - 960) * 64;
    for (int i = 0; i < 128; ++i) {
      int idx = i * 256 + tid, row = r0 + (idx >> 9), c = idx & 511;
      float v = (row < S) ? p.sdc_h0[row * H + c] : p.wld_h0[(row - S) * H + c];
      p.whf[SLOT + row * H + c] = v;
      p.ring[7 * SLOT + row * H + c] = f2bf(v);
    }
  } else {                                  // clear both segb buffers + spinc
    int base = (b - 1024) * 16384;
    for (int i = 0; i < 64; ++i) p.segb[base + i * 256 + tid] = 0u;
    if (b == 1024 && tid < 80) p.spinc[tid] = 0u;
  }
}

// ---------------------------------------------------------------------------
// k_big0: step 0 (full gi from enc + gh from h0, all 4096 rows).
// Grid 512 (64 rt x 8 cg), gload16 staging.
// ---------------------------------------------------------------------------
__global__ __launch_bounds__(256) void k_big0(P p) {
  const int b = blockIdx.x, tid = threadIdx.x;
  const int rt = b >> 3, cg = b & 7;
  const bool sdc = rt < 2;
  const int w = tid >> 6, lr = (tid >> 4) & 3, lc = tid & 15;
  __shared__ u16 sm[16384];
  const u16* WiT = p.WT + (sdc ? 0 : 2) * TH * H;
  const u16* WhT = p.WT + (sdc ? 1 : 3) * TH * H;

  f32x4 ai[3][4], ah[3][4];
  f32x4 zero = {0.f, 0.f, 0.f, 0.f};
#pragma unroll
  for (int g = 0; g < 3; ++g)
#pragma unroll
    for (int mt = 0; mt < 4; ++mt) { ai[g][mt] = zero; ah[g][mt] = zero; }

  for (int pass = 0; pass < 2; ++pass) {
    const u16* A  = pass ? (p.ring + 7 * SLOT + rt * 64 * H) : (p.enc + rt * 64 * H);
    const u16* BT = pass ? WhT : WiT;
    for (int kc = 0; kc < H; kc += 64) {
      __syncthreads();
#pragma unroll
      for (int it = 0; it < 8; ++it) {
        int u = it * 256 + tid;
        int gs = (u ^ (u >> 3)) & 7;
        const u16* src;
        if (u < 512) {
          src = A + (u >> 3) * H + kc + gs * 8;
        } else {
          int v = u - 512;
          int g = v >> 9, m = (v >> 3) & 63;
          src = BT + (g * H + cg * 64 + m) * H + kc + gs * 8;
        }
        gload16(src, sm + (it * 256 + (tid & 192)) * 8);
      }
      __syncthreads();
#pragma unroll
      for (int s2 = 0; s2 < 2; ++s2) {
        const int gk = s2 * 4 + lr;
        short8 av[4], bv[3];
#pragma unroll
        for (int mt = 0; mt < 4; ++mt) av[mt] = lds_frag(sm, mt * 16 + lc, gk);
#pragma unroll
        for (int g = 0; g < 3; ++g) bv[g] = lds_frag(sm + 4096 + g * 4096, w * 16 + lc, gk);
#pragma unroll
        for (int g = 0; g < 3; ++g)
#pragma unroll
          for (int mt = 0; mt < 4; ++mt) {
            f32x4 r = pass ? ah[g][mt] : ai[g][mt];
            r = mfma16(av[mt], bv[g], r);
            if (pass) ah[g][mt] = r; else ai[g][mt] = r;
          }
      }
    }
  }
  const float* bi = sdc ? p.sdcbi : p.wldbi;
  const float* bh = sdc ? p.sdcbh : p.wldbh;
  const int col = cg * 64 + w * 16 + lc;
  const float bir = bi[col], biz = bi[H + col], bin = bi[2 * H + col];
  const float bhr = bh[col], bhz = bh[H + col], bhn = bh[2 * H + col];
#pragma unroll
  for (int mt = 0; mt < 4; ++mt)
#pragma unroll
    for (int i = 0; i < 4; ++i) {
      int grow = rt * 64 + mt * 16 + lr * 4 + i;
      float r = sigm(ai[0][mt][i] + bir + ah[0][mt][i] + bhr);
      float z = sigm(ai[1][mt][i] + biz + ah[1][mt][i] + bhz);
      float n = tanh_(ai[2][mt][i] + bin + r * (ah[2][mt][i] + bhn));
      float h = p.whf[SLOT + grow * H + col];
      float h2 = (1.f - z) * n + z * h;
      p.whf[grow * H + col] = h2;
      p.ring[grow * H + col] = f2bf(h2);
      if (!sdc) {
        int scen = p.seg[grow - S];
        atomicMax(p.segb + scen * H + col, flipf(h2));
      }
    }
}

// ---------------------------------------------------------------------------
// G-tile GEMM: rows rh*64..+64 of sh (from `A`), cols cgx*16 + g*512 of
// wld_WiT; writes dst[row*TH + col] + wldbi. Shared by k_g1 and k_step.
// ---------------------------------------------------------------------------
DEV void g_tile(const P& p, const u16* A, float* dst, int rh, int cgx,
                int tid, u16* sm) {
  const int w = tid >> 6, lr = (tid >> 4) & 3, lc = tid & 15;
  const u16* Wg = p.WT + 2 * TH * H;     // wld_WiT
  f32x4 acc[3];
  f32x4 zero = {0.f, 0.f, 0.f, 0.f};
#pragma unroll
  for (int g = 0; g < 3; ++g) acc[g] = zero;

  for (int kc = 0; kc < H; kc += 64) {
    __syncthreads();
#pragma unroll
    for (int it = 0; it < 4; ++it) {
      int u = it * 256 + tid;
      if (u < 896) {
        const u16* src;
        if (u < 512) {
          int gs = (u ^ (u >> 3)) & 7;
          src = A + (u >> 3) * H + kc + gs * 8;
        } else {
          int v = u - 512;
          int g = v >> 7, m = (v >> 3) & 15, gs = (v ^ (v >> 3)) & 7;
          src = Wg + (g * H + cgx * 16 + m) * H + kc + gs * 8;
        }
        gload16(src, sm + (it * 256 + (tid & 192)) * 8);
      }
    }
    __syncthreads();
#pragma unroll
    for (int s2 = 0; s2 < 2; ++s2) {
      const int gk = s2 * 4 + lr;
      short8 a = lds_frag(sm, w * 16 + lc, gk);
#pragma unroll
      for (int g = 0; g < 3; ++g)
        acc[g] = mfma16(a, lds_frag(sm + 4096 + g * 1024, lc, gk), acc[g]);
    }
  }
#pragma unroll
  for (int g = 0; g < 3; ++g) {
    int ncol = g * H + cgx * 16 + lc;
    float bi = p.wldbi[ncol];
#pragma unroll
    for (int i = 0; i < 4; ++i)
      dst[(rh * 64 + w * 16 + lr * 4 + i) * TH + ncol] = acc[g][i] + bi;
  }
}

// k_g1: G(1) = sh(0) @ wld_WiT + bi -> G buffer 1. Grid 64 (2 rh x 32 cgx).
__global__ __launch_bounds__(256) void k_g1(P p) {
  const int b = blockIdx.x, tid = threadIdx.x;
  __shared__ u16 sm[8192];
  g_tile(p, p.ring + (b >> 5) * 64 * H, p.G + GSZ, b >> 5, b & 31, tid, sm);
}

// ---------------------------------------------------------------------------
// k_step(t): blocks 0..495: world GRU (gh GEMM + gather(G[t&1]) + gates +
//            run-length-merged segmax atomics -> segb[t&1]).
//            blocks 496..559: sdc GRU; then intra-kernel barrier; then clear
//            segb[(t-1)&1] and compute G(t+1) -> G[(t+1)&1].
// ---------------------------------------------------------------------------
__global__ __launch_bounds__(256) void k_step(P p) {
  const int b = blockIdx.x, tid = threadIdx.x;
  const int w = tid >> 6, lr = (tid >> 4) & 3, lc = tid & 15;
  __shared__ u16 sm[16384];
  const int tp = (p.t - 1) & 7, tn = p.t & 7;
  const float* whfP = p.whf + ((p.t - 1) & 1) * SLOT;
  float* whfN = p.whf + (p.t & 1) * SLOT;
  u16* ringN = p.ring + tn * SLOT;

  if (b < 496) {  // ---- world GRU ----
    const int rt = b / 8, cg = b % 8;
    const u16* Abase = p.ring + tp * SLOT + (S + rt * 64) * H;
    const u16* Bbase = p.WT + 3 * TH * H;      // wld_WhT
    f32x4 acc[3][4];
    f32x4 zero = {0.f, 0.f, 0.f, 0.f};
#pragma unroll
    for (int g = 0; g < 3; ++g)
#pragma unroll
      for (int mt = 0; mt < 4; ++mt) acc[g][mt] = zero;

    for (int kc = 0; kc < H; kc += 64) {
      __syncthreads();
#pragma unroll
      for (int it = 0; it < 8; ++it) {
        int u = it * 256 + tid;
        int gs = (u ^ (u >> 3)) & 7;
        const u16* src;
        if (u < 512) {
          src = Abase + (u >> 3) * H + kc + gs * 8;
        } else {
          int v = u - 512;
          int g = v >> 9, m = (v >> 3) & 63;
          src = Bbase + (g * H + cg * 64 + m) * H + kc + gs * 8;
        }
        gload16(src, sm + (it * 256 + (tid & 192)) * 8);
      }
      __syncthreads();
#pragma unroll
      for (int s2 = 0; s2 < 2; ++s2) {
        const int gk = s2 * 4 + lr;
        short8 av[4], bv[3];
#pragma unroll
        for (int mt = 0; mt < 4; ++mt) av[mt] = lds_frag(sm, mt * 16 + lc, gk);
#pragma unroll
        for (int g = 0; g < 3; ++g) bv[g] = lds_frag(sm + 4096 + g * 4096, w * 16 + lc, gk);
#pragma unroll
        for (int g = 0; g < 3; ++g)
#pragma unroll
          for (int mt = 0; mt < 4; ++mt) acc[g][mt] = mfma16(av[mt], bv[g], acc[g][mt]);
      }
    }
    const int col = cg * 64 + w * 16 + lc;
    const float bhr = p.wldbh[col], bhz = p.wldbh[H + col], bhn = p.wldbh[2 * H + col];
    const float* Gbase = p.G + (p.t & 1) * GSZ;
    u32* sb = p.segb + (p.t & 1) * SEGSZ;
    int curSc = -1; float curMx = 0.f;
#pragma unroll
    for (int mt = 0; mt < 4; ++mt)
#pragma unroll
      for (int i = 0; i < 4; ++i) {
        int wrow = rt * 64 + mt * 16 + lr * 4 + i;
        int grow = S + wrow;
        int scen = p.seg[wrow];
        const float* Gr = Gbase + scen * TH;
        float r = sigm(Gr[col]          + acc[0][mt][i] + bhr);
        float z = sigm(Gr[H + col]      + acc[1][mt][i] + bhz);
        float n = tanh_(Gr[2 * H + col] + r * (acc[2][mt][i] + bhn));
        float h = whfP[grow * H + col];
        float h2 = (1.f - z) * n + z * h;
        whfN[grow * H + col] = h2;
        ringN[grow * H + col] = f2bf(h2);
        if (scen == curSc) curMx = fmaxf(curMx, h2);
        else {
          if (curSc >= 0) atomicMax(sb + curSc * H + col, flipf(curMx));
          curSc = scen; curMx = h2;
        }
      }
    atomicMax(sb + curSc * H + col, flipf(curMx));
  } else {        // ---- sdc GRU + barrier + segb clear + G(t+1) ----
    const int ab = b - 496, rh = ab >> 5, cgx = ab & 31;
    const u16* WiT = p.WT;
    const u16* WhT = p.WT + 1 * TH * H;
    u16* ldsA = sm;
    u16* ldsB = sm + 4096;
    f32x4 ai[3], ah[3];
    f32x4 zero = {0.f, 0.f, 0.f, 0.f};
#pragma unroll
    for (int g = 0; g < 3; ++g) { ai[g] = zero; ah[g] = zero; }

    const u32* segP = p.segb + ((p.t - 1) & 1) * SEGSZ;
    for (int pass = 0; pass < 2; ++pass) {
      const u16* Ab = p.ring + tp * SLOT + rh * 64 * H;
      const u16* BT = pass ? WhT : WiT;
      for (int kc = 0; kc < H; kc += 64) {
        __syncthreads();
        if (pass) stage_bf(ldsA, Ab + kc, H, 64, tid);
        else      stage_seg(ldsA, segP + rh * 64 * H + kc, H, tid);
#pragma unroll
        for (int g = 0; g < 3; ++g)
          stage_bf(ldsB + g * 1024, BT + (g * H + cgx * 16) * H + kc, H, 16, tid);
        __syncthreads();
#pragma unroll
        for (int s2 = 0; s2 < 2; ++s2) {
          const int gk = s2 * 4 + lr;
          short8 a = lds_frag(ldsA, w * 16 + lc, gk);
#pragma unroll
          for (int g = 0; g < 3; ++g) {
            f32x4 r = pass ? ah[g] : ai[g];
            r = mfma16(a, lds_frag(ldsB + g * 1024, lc, gk), r);
            if (pass) ah[g] = r; else ai[g] = r;
          }
        }
      }
    }
    const int col = cgx * 16 + lc;
    const float bir = p.sdcbi[col], biz = p.sdcbi[H + col], bin = p.sdcbi[2 * H + col];
    const float bhr = p.sdcbh[col], bhz = p.sdcbh[H + col], bhn = p.sdcbh[2 * H + col];
#pragma unroll
    for (int i = 0; i < 4; ++i) {
      int srow = rh * 64 + w * 16 + lr * 4 + i;
      float r = sigm(ai[0][i] + bir + ah[0][i] + bhr);
      float z = sigm(ai[1][i] + biz + ah[1][i] + bhz);
      float n = tanh_(ai[2][i] + bin + r * (ah[2][i] + bhn));
      float h = whfP[srow * H + col];
      float h2 = (1.f - z) * n + z * h;
      whfN[srow * H + col] = h2;
      ringN[srow * H + col] = f2bf(h2);
    }
    // ---- all-sdc barrier: sh(t) complete & visible ----
    arrive_wait(p.spinc + p.t, tid, 64u);
    // clear segb[(t-1)&1] for reuse at step t+1 (all staging reads are done)
    ((uint4*)(p.segb + ((p.t - 1) & 1) * SEGSZ))[ab * 256 + tid] =
        make_uint4(0u, 0u, 0u, 0u);
    // G(t+1) = sh(t) @ wld_WiT + bi -> buffer (t+1)&1
    g_tile(p, p.ring + tn * SLOT + rh * 64 * H,
           p.G + ((p.t + 1) & 1) * GSZ, rh, cgx, tid, sm);
  }
}

// ---------------------------------------------------------------------------
// k_mlp: per 8-slot batch, layer1 GEMM (128x128 tiles) + fused leaky+layer2
// partials. Grid 1024 = (8 slot x 32 rtile) x 4 ct.
// ---------------------------------------------------------------------------
__global__ __launch_bounds__(256) void k_mlp(P p) {
  const int b = blockIdx.x, tid = threadIdx.x;
  const int rt = b >> 2, ct = b & 3;
  const int slot = rt >> 5, rtile = rt & 31;
  const bool sdc = (rtile == 0);
  const int w = tid >> 6, lr = (tid >> 4) & 3, lc = tid & 15;
  __shared__ u16 sm[16384];
  const u16* A  = p.ring + slot * SLOT + rtile * 128 * H;
  const u16* Bb = p.o1T + (sdc ? 0 : 1) * H * H + (ct * 128) * H;
  const float* o1b = sdc ? p.sdco1b : p.wldo1b;
  const float* o2W = sdc ? p.sdco2W : p.wldo2W;

  f32x4 acc[8][2];
  f32x4 zero = {0.f, 0.f, 0.f, 0.f};
#pragma unroll
  for (int mt = 0; mt < 8; ++mt) { acc[mt][0] = zero; acc[mt][1] = zero; }

  for (int kc = 0; kc < H; kc += 64) {
    __syncthreads();
#pragma unroll
    for (int it = 0; it < 8; ++it) {
      int u = it * 256 + tid;
      int gs = (u ^ (u >> 3)) & 7;
      const u16* src;
      if (u < 1024) src = A  + (u >> 3) * H + kc + gs * 8;
      else          src = Bb + ((u >> 3) & 127) * H + kc + gs * 8;
      gload16(src, sm + (it * 256 + (tid & 192)) * 8);
    }
    __syncthreads();
#pragma unroll
    for (int s2 = 0; s2 < 2; ++s2) {
      const int gk = s2 * 4 + lr;
      short8 av[8], bv[2];
#pragma unroll
      for (int mt = 0; mt < 8; ++mt) av[mt] = lds_frag(sm, mt * 16 + lc, gk);
#pragma unroll
      for (int c2 = 0; c2 < 2; ++c2) bv[c2] = lds_frag(sm + 8192, w * 32 + c2 * 16 + lc, gk);
#pragma unroll
      for (int mt = 0; mt < 8; ++mt)
#pragma unroll
        for (int c2 = 0; c2 < 2; ++c2) acc[mt][c2] = mfma16(av[mt], bv[c2], acc[mt][c2]);
    }
  }
  __syncthreads();
  float* red = (float*)sm;
#pragma unroll
  for (int mt = 0; mt < 8; ++mt) {
    float q0[4] = {0.f, 0.f, 0.f, 0.f}, q1[4] = {0.f, 0.f, 0.f, 0.f};
#pragma unroll
    for (int c2 = 0; c2 < 2; ++c2) {
      int col = ct * 128 + w * 32 + c2 * 16 + lc;
      float b1 = o1b[col], w0 = o2W[col * 2], w1 = o2W[col * 2 + 1];
#pragma unroll
      for (int i = 0; i < 4; ++i) {
        float v = acc[mt][c2][i] + b1;
        v = v > 0.f ? v : 0.1f * v;
        q0[i] += v * w0; q1[i] += v * w1;
      }
    }
#pragma unroll
    for (int off = 1; off < 16; off <<= 1)
#pragma unroll
      for (int i = 0; i < 4; ++i) {
        q0[i] += __shfl_xor(q0[i], off);
        q1[i] += __shfl_xor(q1[i], off);
      }
    if (lc == 0)
#pragma unroll
      for (int i = 0; i < 4; ++i) {
        int row = mt * 16 + lr * 4 + i;
        red[(w * 128 + row) * 2 + 0] = q0[i];
        red[(w * 128 + row) * 2 + 1] = q1[i];
      }
  }
  __syncthreads();
  {
    int row = tid >> 1, od = tid & 1;
    float sum = red[(0 * 128 + row) * 2 + od] + red[(1 * 128 + row) * 2 + od] +
                red[(2 * 128 + row) * 2 + od] + red[(3 * 128 + row) * 2 + od];
    int r = slot * 4096 + rtile * 128 + row;
    p.part[ct * 65536 + r * 2 + od] = sum;
  }
}

// k_mlp2: out = sum of 4 col-quarter partials + o2 bias. Grid 64.
__global__ __launch_bounds__(256) void k_mlp2(P p) {
  const int gtid = blockIdx.x * 256 + threadIdx.x;
  for (int i = gtid; i < 65536; i += 16384) {
    int r = i >> 1, od = i & 1;
    int row = r & 4095, slot = r >> 12;
    float v = p.part[i] + p.part[65536 + i] + p.part[131072 + i] + p.part[196608 + i];
    v += (row < S ? p.sdco2b : p.wldo2b)[od];
    p.out[row * 160 + (p.t + slot) * 2 + od] = v;
  }
}

// ---------------------------------------------------------------------------
extern "C" void kernel_launch(void* const* d_in, const int* in_sizes, int n_in,
                              void* d_out, int out_size, void* d_ws, size_t ws_size,
                              hipStream_t stream) {
  P prm;
  prm.goals  = (const float*)d_in[0];
  prm.dyn    = (const float*)d_in[1];
  prm.ccls   = (const float*)d_in[2];
  prm.inte   = (const float*)d_in[3];
  prm.seg    = (const int*)  d_in[4];
  prm.sdc_h0 = (const float*)d_in[5];
  prm.wld_h0 = (const float*)d_in[6];
  prm.golW   = (const float*)d_in[7];
  prm.golb   = (const float*)d_in[8];
  prm.sdcWi  = (const float*)d_in[9];
  prm.sdcWh  = (const float*)d_in[10];
  prm.sdcbi  = (const float*)d_in[11];
  prm.sdcbh  = (const float*)d_in[12];
  prm.wldWi  = (const float*)d_in[13];
  prm.wldWh  = (const float*)d_in[14];
  prm.wldbi  = (const float*)d_in[15];
  prm.wldbh  = (const float*)d_in[16];
  prm.sdco1W = (const float*)d_in[17];
  prm.sdco1b = (const float*)d_in[18];
  prm.sdco2W = (const float*)d_in[19];
  prm.sdco2b = (const float*)d_in[20];
  prm.wldo1W = (const float*)d_in[21];
  prm.wldo1b = (const float*)d_in[22];
  prm.wldo2W = (const float*)d_in[23];
  prm.wldo2b = (const float*)d_in[24];
  prm.out = (float*)d_out;

  char* ws = (char*)d_ws;
  prm.whf   = (float*)(ws + 0);              // 16,777,216 B
  prm.ring  = (u16*)  (ws + 16777216);       // 33,554,432 B
  prm.enc   = (u16*)  (ws + 50331648);       //  4,194,304 B
  prm.WT    = (u16*)  (ws + 54525952);       //  6,291,456 B
  prm.o1T   = (u16*)  (ws + 60817408);       //  1,048,576 B
  prm.G     = (float*)(ws + 61865984);       //  1,572,864 B (x2 buffers)
  prm.segb  = (u32*)  (ws + 63438848);       //    524,288 B (x2 buffers)
  prm.spinc = (u32*)  (ws + 63963136);       //        320 B
  prm.part  = (float*)(ws + 50331648);       // aliases enc (dead after t=0)

  prm.t = 0;
  k_prep<<<1032, 256, 0, stream>>>(prm);
  k_big0<<<512, 256, 0, stream>>>(prm);
  k_g1<<<64, 256, 0, stream>>>(prm);
  for (int t = 1; t < 80; ++t) {
    prm.t = t;
    k_step<<<560, 256, 0, stream>>>(prm);
    if ((t & 7) == 7) {
      P pm = prm;
      pm.t = t - 7;
      k_mlp<<<1024, 256, 0, stream>>>(pm);
      k_mlp2<<<64, 256, 0, stream>>>(pm);
    }
  }
}